// Round 9
// baseline (123.517 us; speedup 1.0000x reference)
//
#include <hip/hip_runtime.h>
#include <hip/hip_bf16.h>
#include <math.h>

// CerberusSemanticIDBranch — fused prototype-softmax-affinity kernel for MI355X.
//
// out[r,g,:] = (e_g @ M'_g) / sum(e_g),  e_k = exp(l_k - max_g),
// l_k = (x_r . Pn_k) / ((||x_r||+1e-6) * tau),  Pn_k = P_k/(||P_k||+1e-6),
// M'_g = A_g @ P_g / (rowsum(A_g)+1e-6)   (rowsum(A) is constant per group).
//
// Round 9: split at the phase-1/phase-2 seam. Round 8's single kernel is
// grid-capped at 16 waves/CU (512 blocks), and phase 2 (330 MB of stores)
// serializes behind phase 1 inside each block. Now:
//   kernel A (fused_logits, 512x512): phase 1 + softmax (64-row blocks keep
//     x read exactly once), writes softmaxed c as bf16 cb[32768][128] (8 MB).
//   kernel B (fused_out, 1024x512, bounds(512,6) -> 24 waves/CU): pure
//     phase 2; A-frags load directly from cb (already bf16), no barriers.
// Store path keeps round 8's full-line discipline (LDS bounce -> 256B segs).

constexpr int D    = 512;
constexpr int KTOT = 121;
constexpr float TAU = 0.07f;

constexpr int GB[5]  = {0, 2, 17, 57, 97};   // group base row in concat [121] layout
constexpr int GK[5]  = {2, 15, 40, 40, 24};  // prototypes per group
constexpr int GD2[5] = {1, 3, 5, 5, 4};      // second attribute cardinality
constexpr int GNA[5] = {1, 2, 2, 2, 2};      // number of attributes
constexpr int KS0[5] = {0, 0, 0, 1, 3};      // first live 32-wide kstep of group
constexpr int KS1[5] = {1, 1, 2, 4, 4};      // one past last live kstep

using f32x4 = __attribute__((ext_vector_type(4))) float;
using s16x8 = __attribute__((ext_vector_type(8))) short;

__device__ __forceinline__ const float* pick(int k,
    const float* P0, const float* P1, const float* P2, const float* P3, const float* P4,
    int* kl) {
  if (k < 2)  { *kl = k;      return P0; }
  if (k < 17) { *kl = k - 2;  return P1; }
  if (k < 57) { *kl = k - 17; return P2; }
  if (k < 97) { *kl = k - 57; return P3; }
  *kl = k - 97; return P4;
}

__device__ __forceinline__ short f2bf(float f) {
  __hip_bfloat16 h = __float2bfloat16(f);   // RTNE
  return *reinterpret_cast<short*>(&h);
}

// ---- prep 1: inverse norms of the 121 prototype rows --------------------
__global__ void prep_norms(const float* __restrict__ P0, const float* __restrict__ P1,
                           const float* __restrict__ P2, const float* __restrict__ P3,
                           const float* __restrict__ P4, float* __restrict__ invn) {
  int k = blockIdx.x;  // 0..120
  int kl; const float* P = pick(k, P0, P1, P2, P3, P4, &kl);
  const float* row = P + (size_t)kl * D;
  float s = 0.f;
  for (int d = threadIdx.x; d < D; d += 64) { float v = row[d]; s += v * v; }
  #pragma unroll
  for (int m = 1; m < 64; m <<= 1) s += __shfl_xor(s, m);
  if (threadIdx.x == 0) invn[k] = 1.f / (sqrtf(s) + 1e-6f);
}

// ---- prep 2: pnbf = fragment-linear bf16 normalized prototypes ----------
// Block (ct 0..7, s 0..15) of 512 u16: pnbf[(ct*16+s)*512 + lane*8 + j]
//   = Pn[col = ct*16 + (lane&15)][k = s*32 + (lane>>4)*8 + j]  (col>=121 -> 0)
__global__ void prep_pnbf(const float* __restrict__ P0, const float* __restrict__ P1,
                          const float* __restrict__ P2, const float* __restrict__ P3,
                          const float* __restrict__ P4, const float* __restrict__ invn,
                          unsigned short* __restrict__ pnbf) {
  int idx = blockIdx.x * 256 + threadIdx.x;  // 128*512 = 65536
  int blk = idx >> 9, e = idx & 511;
  int lane = e >> 3, j = e & 7;
  int ct = blk >> 4, s = blk & 15;
  int col = ct * 16 + (lane & 15);
  int k   = s * 32 + (lane >> 4) * 8 + j;
  float v = 0.f;
  if (col < KTOT) {
    int kl; const float* P = pick(col, P0, P1, P2, P3, P4, &kl);
    v = P[(size_t)kl * D + k] * invn[col];
  }
  pnbf[idx] = (unsigned short)f2bf(v);
}

// ---- prep 3: mptbf = fragment-linear bf16 block-diag (A@P/rowsum)^T -----
// Block (c 0..159, ks 0..3) of 512 u16: mptbf[(c*4+ks)*512 + lane*8 + j]
//   = Mtilde[k = ks*32 + (lane>>4)*8 + j][gd = c*16 + (lane&15)],
// Mtilde[k][gd] nonzero only for k in [GB[g], GB[g]+GK[g]), g = gd>>9.
__global__ void prep_mptbf(const float* __restrict__ P0, const float* __restrict__ P1,
                           const float* __restrict__ P2, const float* __restrict__ P3,
                           const float* __restrict__ P4, unsigned short* __restrict__ mptbf) {
  int idx = blockIdx.x * 256 + threadIdx.x;  // 640*512 = 327680
  int blk = idx >> 9, e = idx & 511;
  int lane = e >> 3, j = e & 7;
  int c = blk >> 2, ks = blk & 3;
  int gd = c * 16 + (lane & 15);
  int k  = ks * 32 + (lane >> 4) * 8 + j;
  int g = gd >> 9, d = gd & (D - 1);
  float v = 0.f;
  if (k >= GB[g] && k < GB[g] + GK[g]) {
    int kl = k - GB[g];
    const float* P = (g == 0) ? P0 : (g == 1) ? P1 : (g == 2) ? P2 : (g == 3) ? P3 : P4;
    int d2 = GD2[g], na = GNA[g], K = GK[g];
    int a1 = kl / d2, a2 = kl % d2;
    float s = 0.f, m = 0.f;
    for (int jj = 0; jj < K; jj++) {
      float aff;
      if (na == 1) {
        aff = (jj == kl) ? 1.f : 0.f;
      } else {
        int b1 = jj / d2, b2 = jj % d2;
        aff = 0.5f * (float)((a1 == b1) + (a2 == b2));
      }
      s += aff;
      m += aff * P[(size_t)jj * D + d];
    }
    v = m / (s + 1e-6f);
  }
  mptbf[idx] = (unsigned short)f2bf(v);
}

// ---- kernel A: logits + softmax -> cb[32768][128] bf16 ------------------
// 512 blocks x 512 threads (8 waves); block owns 64 rows. Wave (w&3) =
// 16-row slab, (w>>2) = 64-col half; 16 ksteps x 4 MFMA.
__global__ __launch_bounds__(512, 4) void fused_logits(
    const float* __restrict__ x, const unsigned short* __restrict__ pnbf,
    unsigned short* __restrict__ cb) {
  __shared__ float lred[128][65];
  __shared__ float xsqs[64];

  const int tid  = threadIdx.x;
  const int lane = tid & 63;
  const int w    = __builtin_amdgcn_readfirstlane(tid >> 6);
  const int r0   = blockIdx.x * 64;

  const int wr = (w & 3) << 4;   // wave's 16-row slab (block-local)
  const int ch = w >> 2;         // column half
  const int ko = (lane >> 4) << 3;

  // ---- phase 1: 16x64 logit tile via MFMA, K = 512 ----
  {
    const int arow = wr + (lane & 15);
    const float* xrow = x + (size_t)(r0 + arow) * D + ko;

    f32x4 acc[4];
    #pragma unroll
    for (int t = 0; t < 4; ++t) acc[t] = (f32x4){0.f, 0.f, 0.f, 0.f};
    float xsq = 0.f;

    #pragma unroll 4
    for (int s = 0; s < 16; ++s) {
      float4 a0 = *(const float4*)(xrow + s * 32);
      float4 a1 = *(const float4*)(xrow + s * 32 + 4);
      xsq += a0.x * a0.x + a0.y * a0.y + a0.z * a0.z + a0.w * a0.w
           + a1.x * a1.x + a1.y * a1.y + a1.z * a1.z + a1.w * a1.w;
      s16x8 af;
      af[0] = f2bf(a0.x); af[1] = f2bf(a0.y); af[2] = f2bf(a0.z); af[3] = f2bf(a0.w);
      af[4] = f2bf(a1.x); af[5] = f2bf(a1.y); af[6] = f2bf(a1.z); af[7] = f2bf(a1.w);
      #pragma unroll
      for (int t = 0; t < 4; ++t) {
        // fragment-linear B: one contiguous 1KB wave load
        s16x8 bfv = *(const s16x8*)(pnbf + (size_t)(((ch << 2) + t) * 16 + s) * 512 + lane * 8);
        acc[t] = __builtin_amdgcn_mfma_f32_16x16x32_bf16(af, bfv, acc[t], 0, 0, 0);
      }
    }

    // ||x||^2: lanes {l, l^16, l^32, l^48} share the same A-row
    xsq += __shfl_xor(xsq, 16);
    xsq += __shfl_xor(xsq, 32);
    if (w < 4 && lane < 16) xsqs[wr + lane] = xsq;

    // dump C-frags: col = lane&15, row = (lane>>4)*4 + j
    const int drow = wr + ((lane >> 4) << 2);
    #pragma unroll
    for (int t = 0; t < 4; ++t) {
      const int col = (ch << 6) + (t << 4) + (lane & 15);
      #pragma unroll
      for (int j = 0; j < 4; ++j) lred[col][drow + j] = acc[t][j];
    }
  }
  __syncthreads();

  // ---- softmax per group (wave g handles group g; lane = row), 3-pass ----
  if (w < 5) {
    const int g = w;
    const float scale = 1.f / ((sqrtf(xsqs[lane]) + 1e-6f) * TAU);
    float mx = -1e30f;
    for (int kk = 0; kk < GK[g]; ++kk)
      mx = fmaxf(mx, lred[GB[g] + kk][lane]);
    float E = 0.f;
    for (int kk = 0; kk < GK[g]; ++kk) {
      float e = __expf((lred[GB[g] + kk][lane] - mx) * scale);
      lred[GB[g] + kk][lane] = e;
      E += e;
    }
    const float inv = 1.f / E;
    for (int kk = 0; kk < GK[g]; ++kk) lred[GB[g] + kk][lane] *= inv;
  }
  __syncthreads();

  // ---- write cb: thread t -> row r0 + t/8, k-chunk (t%8)*16 (32B store) ----
  {
    const int rl = tid >> 3;           // 0..63
    const int kc = (tid & 7) << 4;     // 0,16,...,112
    unsigned int pk[8];
    #pragma unroll
    for (int jj = 0; jj < 8; ++jj) {
      unsigned int lo = (unsigned short)f2bf(lred[kc + 2 * jj][rl]);
      unsigned int hi = (unsigned short)f2bf(lred[kc + 2 * jj + 1][rl]);
      pk[jj] = lo | (hi << 16);
    }
    unsigned int* cp = (unsigned int*)(cb + (size_t)(r0 + rl) * 128 + kc);
    *(uint4*)(cp + 0) = make_uint4(pk[0], pk[1], pk[2], pk[3]);
    *(uint4*)(cp + 4) = make_uint4(pk[4], pk[5], pk[6], pk[7]);
  }
}

// ---- kernel B phase-2 body: all fragment indices compile-time -----------
// Wave handles 2 strips (64 cols each) of group G: s = G*8 + i*4 + wq.
// C-frags -> per-wave LDS tile (16x68) -> float4 stores, 256B segments.
template <int G>
__device__ __forceinline__ void phase2_group(
    const s16x8 (&af2)[4], const unsigned short* __restrict__ mptbf,
    float* __restrict__ ob, float* __restrict__ obase, int wq, int lane) {
  const int l15 = lane & 15, hi = lane >> 4;
  #pragma unroll 1
  for (int i = 0; i < 2; ++i) {
    const int s = G * 8 + i * 4 + wq;          // strip: cols [64s, 64s+64)
    const unsigned short* bp = mptbf + (size_t)(s * 4) * 4 * 512 + lane * 8;
    f32x4 a0 = (f32x4){0.f, 0.f, 0.f, 0.f}, a1 = a0, a2 = a0, a3 = a0;
    #pragma unroll
    for (int ks = KS0[G]; ks < KS1[G]; ++ks) {  // constexpr -> af2[ks] static
      s16x8 b0 = *(const s16x8*)(bp + (0 * 4 + ks) * 512);
      s16x8 b1 = *(const s16x8*)(bp + (1 * 4 + ks) * 512);
      s16x8 b2 = *(const s16x8*)(bp + (2 * 4 + ks) * 512);
      s16x8 b3 = *(const s16x8*)(bp + (3 * 4 + ks) * 512);
      a0 = __builtin_amdgcn_mfma_f32_16x16x32_bf16(af2[ks], b0, a0, 0, 0, 0);
      a1 = __builtin_amdgcn_mfma_f32_16x16x32_bf16(af2[ks], b1, a1, 0, 0, 0);
      a2 = __builtin_amdgcn_mfma_f32_16x16x32_bf16(af2[ks], b2, a2, 0, 0, 0);
      a3 = __builtin_amdgcn_mfma_f32_16x16x32_bf16(af2[ks], b3, a3, 0, 0, 0);
    }
    // scatter C-frags into LDS: row = hi*4+j, col = t*16 + l15
    #pragma unroll
    for (int j = 0; j < 4; ++j) {
      const int row = hi * 4 + j;
      ob[row * 68 +  0 + l15] = a0[j];
      ob[row * 68 + 16 + l15] = a1[j];
      ob[row * 68 + 32 + l15] = a2[j];
      ob[row * 68 + 48 + l15] = a3[j];
    }
    // read back row-major and store: 4 rows x 256B contiguous per instr
    float* gp = obase + (size_t)s * 64 + l15 * 4;
    #pragma unroll
    for (int i2 = 0; i2 < 4; ++i2) {
      const int row = i2 * 4 + hi;
      float4 v = *(float4*)&ob[row * 68 + l15 * 4];
      *(float4*)(gp + (size_t)row * (5 * D)) = v;
    }
  }
}

// ---- kernel B: out[32 x 2560] per block = C @ Btilde --------------------
// 1024 blocks x 512 threads (8 waves); block owns 32 rows. Wave: slab =
// w&1 (16 rows), wq = w>>1 (strip parity, 0..3). No barriers.
__global__ __launch_bounds__(512, 6) void fused_out(
    const unsigned short* __restrict__ cb, const unsigned short* __restrict__ mptbf,
    float* __restrict__ out) {
  __shared__ __align__(16) float smem[8 * 16 * 68];   // per-wave bounce tiles

  const int tid  = threadIdx.x;
  const int lane = tid & 63;
  const int w    = __builtin_amdgcn_readfirstlane(tid >> 6);
  const int slab = w & 1;
  const int wq   = w >> 1;
  const int rg0  = blockIdx.x * 32 + slab * 16;   // wave's 16 global rows

  // A-frags straight from cb (already bf16): lane l -> row rg0 + (l&15),
  // k-chunk ks*32 + (l>>4)*8
  s16x8 af2[4];
  {
    const unsigned short* cp = cb + (size_t)(rg0 + (lane & 15)) * 128 + ((lane >> 4) << 3);
    #pragma unroll
    for (int ks = 0; ks < 4; ++ks) af2[ks] = *(const s16x8*)(cp + ks * 32);
  }

  float* ob    = smem + w * (16 * 68);
  float* obase = out + (size_t)rg0 * (5 * D);

  phase2_group<0>(af2, mptbf, ob, obase, wq, lane);
  phase2_group<1>(af2, mptbf, ob, obase, wq, lane);
  phase2_group<2>(af2, mptbf, ob, obase, wq, lane);
  phase2_group<3>(af2, mptbf, ob, obase, wq, lane);
  phase2_group<4>(af2, mptbf, ob, obase, wq, lane);
}

extern "C" void kernel_launch(void* const* d_in, const int* in_sizes, int n_in,
                              void* d_out, int out_size, void* d_ws, size_t ws_size,
                              hipStream_t stream) {
  const float* x  = (const float*)d_in[0];
  const float* P0 = (const float*)d_in[1];  // gender [2,512]
  const float* P1 = (const float*)d_in[2];  // hair   [15,512]
  const float* P2 = (const float*)d_in[3];  // top    [40,512]
  const float* P3 = (const float*)d_in[4];  // pants  [40,512]
  const float* P4 = (const float*)d_in[5];  // shoes  [24,512]
  float* out = (float*)d_out;

  unsigned short* pnbf  = (unsigned short*)d_ws;       // 128*512  u16 = 128 KiB
  unsigned short* mptbf = pnbf + 128 * 512;            // 640*512  u16 = 640 KiB
  unsigned short* cb    = mptbf + 640 * 512;           // 32768*128 u16 = 8 MiB
  float* invn = (float*)(cb + (size_t)32768 * 128);    // 121 floats

  prep_norms<<<dim3(121), dim3(64), 0, stream>>>(P0, P1, P2, P3, P4, invn);
  prep_pnbf<<<dim3(256), dim3(256), 0, stream>>>(P0, P1, P2, P3, P4, invn, pnbf);
  prep_mptbf<<<dim3(1280), dim3(256), 0, stream>>>(P0, P1, P2, P3, P4, mptbf);
  fused_logits<<<dim3(512), dim3(512), 0, stream>>>(x, pnbf, cb);
  fused_out<<<dim3(1024), dim3(512), 0, stream>>>(cb, mptbf, out);
}

// Round 11
// 117.658 us; speedup vs baseline: 1.0498x; 1.0498x over previous
//
#include <hip/hip_runtime.h>
#include <hip/hip_bf16.h>
#include <math.h>

// CerberusSemanticIDBranch — fused prototype-softmax-affinity kernel for MI355X.
//
// out[r,g,:] = (e_g @ M'_g) / sum(e_g),  e_k = exp(l_k - max_g),
// l_k = (x_r . Pn_k) / ((||x_r||+1e-6) * tau),  Pn_k = P_k/(||P_k||+1e-6),
// M'_g = A_g @ P_g / (rowsum(A_g)+1e-6)   (rowsum(A) is constant per group).
//
// Round 11 = round 10 with the compile fix: __builtin_nontemporal_store
// requires a clang ext_vector pointer (f32x4), not HIP's float4 class.
//  (a) phase-2 MFMA operands SWAPPED: mfma(mptbf_frag, c_frag, acc) -> lane
//      holds 4 consecutive out cols of one out row -> LDS bounce writes are
//      4x ds_write_b128 instead of 16x scalar ds_write_b32.
//  (b) output stores non-temporal (write-once data; don't evict hot
//      pnbf/mptbf/x lines from L2).

constexpr int D    = 512;
constexpr int KTOT = 121;
constexpr float TAU = 0.07f;

constexpr int GB[5]  = {0, 2, 17, 57, 97};   // group base row in concat [121] layout
constexpr int GK[5]  = {2, 15, 40, 40, 24};  // prototypes per group
constexpr int GD2[5] = {1, 3, 5, 5, 4};      // second attribute cardinality
constexpr int GNA[5] = {1, 2, 2, 2, 2};      // number of attributes
constexpr int KS0[5] = {0, 0, 0, 1, 3};      // first live 32-wide kstep of group
constexpr int KS1[5] = {1, 1, 2, 4, 4};      // one past last live kstep

using f32x4 = __attribute__((ext_vector_type(4))) float;
using s16x8 = __attribute__((ext_vector_type(8))) short;

__device__ __forceinline__ const float* pick(int k,
    const float* P0, const float* P1, const float* P2, const float* P3, const float* P4,
    int* kl) {
  if (k < 2)  { *kl = k;      return P0; }
  if (k < 17) { *kl = k - 2;  return P1; }
  if (k < 57) { *kl = k - 17; return P2; }
  if (k < 97) { *kl = k - 57; return P3; }
  *kl = k - 97; return P4;
}

__device__ __forceinline__ short f2bf(float f) {
  __hip_bfloat16 h = __float2bfloat16(f);   // RTNE
  return *reinterpret_cast<short*>(&h);
}

// ---- prep 1: inverse norms of the 121 prototype rows --------------------
__global__ void prep_norms(const float* __restrict__ P0, const float* __restrict__ P1,
                           const float* __restrict__ P2, const float* __restrict__ P3,
                           const float* __restrict__ P4, float* __restrict__ invn) {
  int k = blockIdx.x;  // 0..120
  int kl; const float* P = pick(k, P0, P1, P2, P3, P4, &kl);
  const float* row = P + (size_t)kl * D;
  float s = 0.f;
  for (int d = threadIdx.x; d < D; d += 64) { float v = row[d]; s += v * v; }
  #pragma unroll
  for (int m = 1; m < 64; m <<= 1) s += __shfl_xor(s, m);
  if (threadIdx.x == 0) invn[k] = 1.f / (sqrtf(s) + 1e-6f);
}

// ---- prep 2: pnbf = fragment-linear bf16 normalized prototypes ----------
// Block (ct 0..7, s 0..15) of 512 u16: pnbf[(ct*16+s)*512 + lane*8 + j]
//   = Pn[col = ct*16 + (lane&15)][k = s*32 + (lane>>4)*8 + j]  (col>=121 -> 0)
__global__ void prep_pnbf(const float* __restrict__ P0, const float* __restrict__ P1,
                          const float* __restrict__ P2, const float* __restrict__ P3,
                          const float* __restrict__ P4, const float* __restrict__ invn,
                          unsigned short* __restrict__ pnbf) {
  int idx = blockIdx.x * 256 + threadIdx.x;  // 128*512 = 65536
  int blk = idx >> 9, e = idx & 511;
  int lane = e >> 3, j = e & 7;
  int ct = blk >> 4, s = blk & 15;
  int col = ct * 16 + (lane & 15);
  int k   = s * 32 + (lane >> 4) * 8 + j;
  float v = 0.f;
  if (col < KTOT) {
    int kl; const float* P = pick(col, P0, P1, P2, P3, P4, &kl);
    v = P[(size_t)kl * D + k] * invn[col];
  }
  pnbf[idx] = (unsigned short)f2bf(v);
}

// ---- prep 3: mptbf = fragment-linear bf16 block-diag (A@P/rowsum)^T -----
// Block (c 0..159, ks 0..3) of 512 u16: mptbf[(c*4+ks)*512 + lane*8 + j]
//   = Mtilde[k = ks*32 + (lane>>4)*8 + j][gd = c*16 + (lane&15)],
// Mtilde[k][gd] nonzero only for k in [GB[g], GB[g]+GK[g]), g = gd>>9.
// (Same layout serves as the phase-2 A-operand: for 16x16x32, A[m][k] with
//  m = lane&15, k-octet = lane>>4 is the identical lane map.)
__global__ void prep_mptbf(const float* __restrict__ P0, const float* __restrict__ P1,
                           const float* __restrict__ P2, const float* __restrict__ P3,
                           const float* __restrict__ P4, unsigned short* __restrict__ mptbf) {
  int idx = blockIdx.x * 256 + threadIdx.x;  // 640*512 = 327680
  int blk = idx >> 9, e = idx & 511;
  int lane = e >> 3, j = e & 7;
  int c = blk >> 2, ks = blk & 3;
  int gd = c * 16 + (lane & 15);
  int k  = ks * 32 + (lane >> 4) * 8 + j;
  int g = gd >> 9, d = gd & (D - 1);
  float v = 0.f;
  if (k >= GB[g] && k < GB[g] + GK[g]) {
    int kl = k - GB[g];
    const float* P = (g == 0) ? P0 : (g == 1) ? P1 : (g == 2) ? P2 : (g == 3) ? P3 : P4;
    int d2 = GD2[g], na = GNA[g], K = GK[g];
    int a1 = kl / d2, a2 = kl % d2;
    float s = 0.f, m = 0.f;
    for (int jj = 0; jj < K; jj++) {
      float aff;
      if (na == 1) {
        aff = (jj == kl) ? 1.f : 0.f;
      } else {
        int b1 = jj / d2, b2 = jj % d2;
        aff = 0.5f * (float)((a1 == b1) + (a2 == b2));
      }
      s += aff;
      m += aff * P[(size_t)jj * D + d];
    }
    v = m / (s + 1e-6f);
  }
  mptbf[idx] = (unsigned short)f2bf(v);
}

// ---- phase 2 per-group body: all fragment indices compile-time ----------
// Wave handles 4 strips (64 cols each) of group G: s = G*8 + i*2 + ch.
// SWAPPED mfma: D = mptbf_frag (A) x c_frag (B) -> lane holds out row
// (lane&15), 4 consecutive cols 4*(lane>>4)+reg per tile. LDS bounce:
// 4x ds_write_b128, then row-major read-back -> 256B-segment nt stores.
template <int G>
__device__ __forceinline__ void phase2_group(
    const s16x8 (&af2)[4], const unsigned short* __restrict__ mptbf,
    float* __restrict__ ob, float* __restrict__ obase, int ch, int lane) {
  const int l15 = lane & 15, hi = lane >> 4;
  #pragma unroll 1
  for (int i = 0; i < 4; ++i) {
    const int s = G * 8 + i * 2 + ch;          // strip: cols [64s, 64s+64)
    const unsigned short* bp = mptbf + (size_t)(s * 4) * 4 * 512 + lane * 8;
    f32x4 a0 = (f32x4){0.f, 0.f, 0.f, 0.f}, a1 = a0, a2 = a0, a3 = a0;
    #pragma unroll
    for (int ks = KS0[G]; ks < KS1[G]; ++ks) {  // constexpr -> af2[ks] static
      s16x8 b0 = *(const s16x8*)(bp + (0 * 4 + ks) * 512);
      s16x8 b1 = *(const s16x8*)(bp + (1 * 4 + ks) * 512);
      s16x8 b2 = *(const s16x8*)(bp + (2 * 4 + ks) * 512);
      s16x8 b3 = *(const s16x8*)(bp + (3 * 4 + ks) * 512);
      a0 = __builtin_amdgcn_mfma_f32_16x16x32_bf16(b0, af2[ks], a0, 0, 0, 0);
      a1 = __builtin_amdgcn_mfma_f32_16x16x32_bf16(b1, af2[ks], a1, 0, 0, 0);
      a2 = __builtin_amdgcn_mfma_f32_16x16x32_bf16(b2, af2[ks], a2, 0, 0, 0);
      a3 = __builtin_amdgcn_mfma_f32_16x16x32_bf16(b3, af2[ks], a3, 0, 0, 0);
    }
    // bounce: lane owns row l15, cols {16t + 4hi .. +3} -> 4 b128 writes
    *(f32x4*)&ob[l15 * 68 +  0 + hi * 4] = a0;
    *(f32x4*)&ob[l15 * 68 + 16 + hi * 4] = a1;
    *(f32x4*)&ob[l15 * 68 + 32 + hi * 4] = a2;
    *(f32x4*)&ob[l15 * 68 + 48 + hi * 4] = a3;
    // read back row-major and store: 4 rows x 256B contiguous per instr
    float* gp = obase + (size_t)s * 64 + l15 * 4;
    #pragma unroll
    for (int i2 = 0; i2 < 4; ++i2) {
      const int row = i2 * 4 + hi;
      f32x4 v = *(const f32x4*)&ob[row * 68 + l15 * 4];
      __builtin_nontemporal_store(v, (f32x4*)(gp + (size_t)row * (5 * D)));
    }
  }
}

// ---- main fused kernel --------------------------------------------------
// 512 blocks x 512 threads (8 waves); block owns 64 rows. Phase 1: wave
// (w&3) = 16-row slab, (w>>2) = 64-col half, 16 ksteps x 4 MFMA. Phase 2:
// wave takes 4 strips per group (parity w>>2).
__global__ __launch_bounds__(512, 4) void fused_main(
    const float* __restrict__ x, const unsigned short* __restrict__ pnbf,
    const unsigned short* __restrict__ mptbf, float* __restrict__ out) {
  // smem serves as lred[128][65] (phase 1 + softmax + A-build), then
  // per-wave 16x68 store-bounce tiles (phase 2). 8704 f32 = 34816 B.
  __shared__ __align__(16) float smem[8704];
  __shared__ float xsqs[64];
  float (*lred)[65] = (float (*)[65])smem;

  const int tid  = threadIdx.x;
  const int lane = tid & 63;
  const int w    = __builtin_amdgcn_readfirstlane(tid >> 6);
  const int r0   = blockIdx.x * 64;

  const int wr = (w & 3) << 4;   // wave's 16-row slab (block-local)
  const int ch = w >> 2;         // column half / strip parity
  const int ko = (lane >> 4) << 3;

  // ---- phase 1: 16x64 logit tile via MFMA, K = 512 ----
  {
    const int arow = wr + (lane & 15);
    const float* xrow = x + (size_t)(r0 + arow) * D + ko;

    f32x4 acc[4];
    #pragma unroll
    for (int t = 0; t < 4; ++t) acc[t] = (f32x4){0.f, 0.f, 0.f, 0.f};
    float xsq = 0.f;

    #pragma unroll 4
    for (int s = 0; s < 16; ++s) {
      float4 a0 = *(const float4*)(xrow + s * 32);
      float4 a1 = *(const float4*)(xrow + s * 32 + 4);
      xsq += a0.x * a0.x + a0.y * a0.y + a0.z * a0.z + a0.w * a0.w
           + a1.x * a1.x + a1.y * a1.y + a1.z * a1.z + a1.w * a1.w;
      s16x8 af;
      af[0] = f2bf(a0.x); af[1] = f2bf(a0.y); af[2] = f2bf(a0.z); af[3] = f2bf(a0.w);
      af[4] = f2bf(a1.x); af[5] = f2bf(a1.y); af[6] = f2bf(a1.z); af[7] = f2bf(a1.w);
      #pragma unroll
      for (int t = 0; t < 4; ++t) {
        // fragment-linear B: one contiguous 1KB wave load
        s16x8 bfv = *(const s16x8*)(pnbf + (size_t)(((ch << 2) + t) * 16 + s) * 512 + lane * 8);
        acc[t] = __builtin_amdgcn_mfma_f32_16x16x32_bf16(af, bfv, acc[t], 0, 0, 0);
      }
    }

    // ||x||^2: lanes {l, l^16, l^32, l^48} share the same A-row
    xsq += __shfl_xor(xsq, 16);
    xsq += __shfl_xor(xsq, 32);
    if (w < 4 && lane < 16) xsqs[wr + lane] = xsq;

    // dump C-frags: col = lane&15, row = (lane>>4)*4 + j
    const int drow = wr + ((lane >> 4) << 2);
    #pragma unroll
    for (int t = 0; t < 4; ++t) {
      const int col = (ch << 6) + (t << 4) + (lane & 15);
      #pragma unroll
      for (int j = 0; j < 4; ++j) lred[col][drow + j] = acc[t][j];
    }
  }
  __syncthreads();

  // ---- softmax per group (wave g handles group g; lane = row), 3-pass ----
  if (w < 5) {
    const int g = w;
    const float scale = 1.f / ((sqrtf(xsqs[lane]) + 1e-6f) * TAU);
    float mx = -1e30f;
    for (int kk = 0; kk < GK[g]; ++kk)
      mx = fmaxf(mx, lred[GB[g] + kk][lane]);
    float E = 0.f;
    for (int kk = 0; kk < GK[g]; ++kk) {
      float e = __expf((lred[GB[g] + kk][lane] - mx) * scale);
      lred[GB[g] + kk][lane] = e;
      E += e;
    }
    const float inv = 1.f / E;
    for (int kk = 0; kk < GK[g]; ++kk) lred[GB[g] + kk][lane] *= inv;
  }
  __syncthreads();

  // ---- A-frags for phase 2 (c as MFMA B-operand; lred still live) ----
  s16x8 af2[4];
  {
    const int ar = wr + (lane & 15);
    #pragma unroll
    for (int s = 0; s < 4; ++s) {
      const int kbase = s * 32 + ko;
      s16x8 f;
      #pragma unroll
      for (int j = 0; j < 8; ++j) f[j] = f2bf(lred[kbase + j][ar]);
      af2[s] = f;
    }
  }
  __syncthreads();   // lred dead; smem becomes per-wave store-bounce tiles

  // ---- phase 2: out[64 x 2560] = C @ Btilde, strip-wise full-line stores --
  {
    float* ob    = smem + w * (16 * 68);                  // per-wave 16x68 tile
    float* obase = out + (size_t)(r0 + wr) * (5 * D);     // slab's global base

    phase2_group<0>(af2, mptbf, ob, obase, ch, lane);
    phase2_group<1>(af2, mptbf, ob, obase, ch, lane);
    phase2_group<2>(af2, mptbf, ob, obase, ch, lane);
    phase2_group<3>(af2, mptbf, ob, obase, ch, lane);
    phase2_group<4>(af2, mptbf, ob, obase, ch, lane);
  }
}

extern "C" void kernel_launch(void* const* d_in, const int* in_sizes, int n_in,
                              void* d_out, int out_size, void* d_ws, size_t ws_size,
                              hipStream_t stream) {
  const float* x  = (const float*)d_in[0];
  const float* P0 = (const float*)d_in[1];  // gender [2,512]
  const float* P1 = (const float*)d_in[2];  // hair   [15,512]
  const float* P2 = (const float*)d_in[3];  // top    [40,512]
  const float* P3 = (const float*)d_in[4];  // pants  [40,512]
  const float* P4 = (const float*)d_in[5];  // shoes  [24,512]
  float* out = (float*)d_out;

  unsigned short* pnbf  = (unsigned short*)d_ws;       // 128*512  u16 = 128 KiB
  unsigned short* mptbf = pnbf + 128 * 512;            // 640*512  u16 = 640 KiB
  float* invn = (float*)(mptbf + 640 * 512);           // 121 floats

  prep_norms<<<dim3(121), dim3(64), 0, stream>>>(P0, P1, P2, P3, P4, invn);
  prep_pnbf<<<dim3(256), dim3(256), 0, stream>>>(P0, P1, P2, P3, P4, invn, pnbf);
  prep_mptbf<<<dim3(1280), dim3(256), 0, stream>>>(P0, P1, P2, P3, P4, mptbf);
  fused_main<<<dim3(512), dim3(512), 0, stream>>>(x, pnbf, mptbf, out);
}

// Round 12
// 115.977 us; speedup vs baseline: 1.0650x; 1.0145x over previous
//
#include <hip/hip_runtime.h>
#include <hip/hip_bf16.h>
#include <math.h>

// CerberusSemanticIDBranch — fused prototype-softmax-affinity kernel for MI355X.
//
// out[r,g,:] = (e_g @ M'_g) / sum(e_g),  e_k = exp(l_k - max_g),
// l_k = (x_r . Pn_k) / ((||x_r||+1e-6) * tau),  Pn_k = P_k/(||P_k||+1e-6),
// M'_g = A_g @ P_g / (rowsum(A_g)+1e-6)   (rowsum(A) is constant per group).
//
// Round 12: (a) all preps merged into ONE kernel (8 pnbf blocks compute the
// row norms in-block; 640 mptbf blocks) -> 2 launches per replay instead of
// 4. (b) fused_main moves to 32-row blocks x 256 threads (4 waves), grid
// 1024 -> 4 blocks/CU (vs 2): per-wave work identical to round 11 (slab =
// w&1, col-half/strip-parity = w>>1, 20 phase-2 strips/wave), but the CU now
// holds independent blocks at different phase positions, mixing the
// load-heavy phase 1 with the store-heavy phase 2. x-reuse stays 2x
// (avoids round 7's 4x x-read blowup). LDS ~17.5 KB.

constexpr int D    = 512;
constexpr int KTOT = 121;
constexpr float TAU = 0.07f;

constexpr int GB[5]  = {0, 2, 17, 57, 97};   // group base row in concat [121] layout
constexpr int GK[5]  = {2, 15, 40, 40, 24};  // prototypes per group
constexpr int GD2[5] = {1, 3, 5, 5, 4};      // second attribute cardinality
constexpr int GNA[5] = {1, 2, 2, 2, 2};      // number of attributes
constexpr int KS0[5] = {0, 0, 0, 1, 3};      // first live 32-wide kstep of group
constexpr int KS1[5] = {1, 1, 2, 4, 4};      // one past last live kstep

using f32x4 = __attribute__((ext_vector_type(4))) float;
using s16x8 = __attribute__((ext_vector_type(8))) short;

__device__ __forceinline__ const float* pick(int k,
    const float* P0, const float* P1, const float* P2, const float* P3, const float* P4,
    int* kl) {
  if (k < 2)  { *kl = k;      return P0; }
  if (k < 17) { *kl = k - 2;  return P1; }
  if (k < 57) { *kl = k - 17; return P2; }
  if (k < 97) { *kl = k - 57; return P3; }
  *kl = k - 97; return P4;
}

__device__ __forceinline__ short f2bf(float f) {
  __hip_bfloat16 h = __float2bfloat16(f);   // RTNE
  return *reinterpret_cast<short*>(&h);
}

// ---- merged prep kernel -------------------------------------------------
// Blocks 0..7   (ct): pnbf 16-col slab — compute the 16 prototype-row norms
//                     in-block, then write the 16 fragment-linear s-blocks.
// Blocks 8..647 (c2): one 512-u16 fragment-linear block of mptbf.
// pnbf[(ct*16+s)*512 + lane*8 + j] = Pn[ct*16+(lane&15)][s*32+(lane>>4)*8+j]
// mptbf[(c*4+ks)*512 + lane*8 + j] = Mtilde[ks*32+(lane>>4)*8+j][c*16+(lane&15)]
__global__ __launch_bounds__(256) void prep_all(
    const float* __restrict__ P0, const float* __restrict__ P1,
    const float* __restrict__ P2, const float* __restrict__ P3,
    const float* __restrict__ P4, unsigned short* __restrict__ pnbf,
    unsigned short* __restrict__ mptbf) {
  const int tid = threadIdx.x;
  if (blockIdx.x < 8) {
    const int ct = blockIdx.x;
    __shared__ float lsum[16][17];
    __shared__ float linv[16];
    // norms: thread (i = t>>4, part = t&15) sums 32 elems of row ct*16+i
    {
      const int i = tid >> 4, part = tid & 15;
      const int col = ct * 16 + i;
      float s = 0.f;
      if (col < KTOT) {
        int kl; const float* P = pick(col, P0, P1, P2, P3, P4, &kl);
        const float* row = P + (size_t)kl * D + part * 32;
        #pragma unroll
        for (int e = 0; e < 32; ++e) { float v = row[e]; s += v * v; }
      }
      lsum[i][part] = s;
    }
    __syncthreads();
    if (tid < 16) {
      float s = 0.f;
      #pragma unroll
      for (int p = 0; p < 16; ++p) s += lsum[tid][p];
      linv[tid] = 1.f / (sqrtf(s) + 1e-6f);
    }
    __syncthreads();
    // write the 16 s-blocks of this col-slab
    for (int s = 0; s < 16; ++s) {
      #pragma unroll
      for (int half = 0; half < 2; ++half) {
        const int e = tid + half * 256;
        const int lane = e >> 3, j = e & 7;
        const int col = ct * 16 + (lane & 15);
        const int k   = s * 32 + (lane >> 4) * 8 + j;
        float v = 0.f;
        if (col < KTOT) {
          int kl; const float* P = pick(col, P0, P1, P2, P3, P4, &kl);
          v = P[(size_t)kl * D + k] * linv[lane & 15];
        }
        pnbf[(size_t)(ct * 16 + s) * 512 + e] = (unsigned short)f2bf(v);
      }
    }
  } else {
    const int c2 = blockIdx.x - 8;           // 0..639
    const int c = c2 >> 2, ks = c2 & 3;
    #pragma unroll
    for (int half = 0; half < 2; ++half) {
      const int e = tid + half * 256;
      const int lane = e >> 3, j = e & 7;
      const int gd = c * 16 + (lane & 15);
      const int k  = ks * 32 + (lane >> 4) * 8 + j;
      const int g = gd >> 9, d = gd & (D - 1);
      float v = 0.f;
      if (k >= GB[g] && k < GB[g] + GK[g]) {
        int kl = k - GB[g];
        const float* P = (g == 0) ? P0 : (g == 1) ? P1 : (g == 2) ? P2 : (g == 3) ? P3 : P4;
        int d2 = GD2[g], na = GNA[g], K = GK[g];
        int a1 = kl / d2, a2 = kl % d2;
        float s = 0.f, m = 0.f;
        for (int jj = 0; jj < K; jj++) {
          float aff;
          if (na == 1) {
            aff = (jj == kl) ? 1.f : 0.f;
          } else {
            int b1 = jj / d2, b2 = jj % d2;
            aff = 0.5f * (float)((a1 == b1) + (a2 == b2));
          }
          s += aff;
          m += aff * P[(size_t)jj * D + d];
        }
        v = m / (s + 1e-6f);
      }
      mptbf[(size_t)c2 * 512 + e] = (unsigned short)f2bf(v);
    }
  }
}

// ---- phase 2 per-group body: all fragment indices compile-time ----------
// Wave handles 4 strips (64 cols each) of group G: s = G*8 + i*2 + ch.
// SWAPPED mfma: D = mptbf_frag (A) x c_frag (B) -> lane holds out row
// (lane&15), 4 consecutive cols 4*(lane>>4)+reg per tile. LDS bounce:
// 4x ds_write_b128, then row-major read-back -> 256B-segment nt stores.
template <int G>
__device__ __forceinline__ void phase2_group(
    const s16x8 (&af2)[4], const unsigned short* __restrict__ mptbf,
    float* __restrict__ ob, float* __restrict__ obase, int ch, int lane) {
  const int l15 = lane & 15, hi = lane >> 4;
  #pragma unroll 1
  for (int i = 0; i < 4; ++i) {
    const int s = G * 8 + i * 2 + ch;          // strip: cols [64s, 64s+64)
    const unsigned short* bp = mptbf + (size_t)(s * 4) * 4 * 512 + lane * 8;
    f32x4 a0 = (f32x4){0.f, 0.f, 0.f, 0.f}, a1 = a0, a2 = a0, a3 = a0;
    #pragma unroll
    for (int ks = KS0[G]; ks < KS1[G]; ++ks) {  // constexpr -> af2[ks] static
      s16x8 b0 = *(const s16x8*)(bp + (0 * 4 + ks) * 512);
      s16x8 b1 = *(const s16x8*)(bp + (1 * 4 + ks) * 512);
      s16x8 b2 = *(const s16x8*)(bp + (2 * 4 + ks) * 512);
      s16x8 b3 = *(const s16x8*)(bp + (3 * 4 + ks) * 512);
      a0 = __builtin_amdgcn_mfma_f32_16x16x32_bf16(b0, af2[ks], a0, 0, 0, 0);
      a1 = __builtin_amdgcn_mfma_f32_16x16x32_bf16(b1, af2[ks], a1, 0, 0, 0);
      a2 = __builtin_amdgcn_mfma_f32_16x16x32_bf16(b2, af2[ks], a2, 0, 0, 0);
      a3 = __builtin_amdgcn_mfma_f32_16x16x32_bf16(b3, af2[ks], a3, 0, 0, 0);
    }
    // bounce: lane owns row l15, cols {16t + 4hi .. +3} -> 4 b128 writes
    *(f32x4*)&ob[l15 * 68 +  0 + hi * 4] = a0;
    *(f32x4*)&ob[l15 * 68 + 16 + hi * 4] = a1;
    *(f32x4*)&ob[l15 * 68 + 32 + hi * 4] = a2;
    *(f32x4*)&ob[l15 * 68 + 48 + hi * 4] = a3;
    // read back row-major and store: 4 rows x 256B contiguous per instr
    float* gp = obase + (size_t)s * 64 + l15 * 4;
    #pragma unroll
    for (int i2 = 0; i2 < 4; ++i2) {
      const int row = i2 * 4 + hi;
      f32x4 v = *(const f32x4*)&ob[row * 68 + l15 * 4];
      __builtin_nontemporal_store(v, (f32x4*)(gp + (size_t)row * (5 * D)));
    }
  }
}

// ---- main fused kernel --------------------------------------------------
// 1024 blocks x 256 threads (4 waves); block owns 32 rows. Phase 1: wave
// slab = w&1 (16 rows), ch = w>>1 (64-col half), 16 ksteps x 4 MFMA.
// Phase 2: wave takes 4 strips per group (parity ch). Per-wave work is
// identical to round 11; blocks/CU doubles to 4 for phase mixing.
__global__ __launch_bounds__(256, 4) void fused_main(
    const float* __restrict__ x, const unsigned short* __restrict__ pnbf,
    const unsigned short* __restrict__ mptbf, float* __restrict__ out) {
  // smem: lred[128][33] (16896B) then per-wave 16x68 bounce tiles (17408B).
  __shared__ __align__(16) float smem[4352];
  __shared__ float xsqs[32];
  float (*lred)[33] = (float (*)[33])smem;

  const int tid  = threadIdx.x;
  const int lane = tid & 63;
  const int w    = __builtin_amdgcn_readfirstlane(tid >> 6);
  const int r0   = blockIdx.x * 32;

  const int wr = (w & 1) << 4;   // wave's 16-row slab (block-local)
  const int ch = w >> 1;         // column half / strip parity
  const int ko = (lane >> 4) << 3;

  // ---- phase 1: 16x64 logit tile via MFMA, K = 512 ----
  {
    const int arow = wr + (lane & 15);
    const float* xrow = x + (size_t)(r0 + arow) * D + ko;

    f32x4 acc[4];
    #pragma unroll
    for (int t = 0; t < 4; ++t) acc[t] = (f32x4){0.f, 0.f, 0.f, 0.f};
    float xsq = 0.f;

    #pragma unroll 4
    for (int s = 0; s < 16; ++s) {
      float4 a0 = *(const float4*)(xrow + s * 32);
      float4 a1 = *(const float4*)(xrow + s * 32 + 4);
      xsq += a0.x * a0.x + a0.y * a0.y + a0.z * a0.z + a0.w * a0.w
           + a1.x * a1.x + a1.y * a1.y + a1.z * a1.z + a1.w * a1.w;
      s16x8 af;
      af[0] = f2bf(a0.x); af[1] = f2bf(a0.y); af[2] = f2bf(a0.z); af[3] = f2bf(a0.w);
      af[4] = f2bf(a1.x); af[5] = f2bf(a1.y); af[6] = f2bf(a1.z); af[7] = f2bf(a1.w);
      #pragma unroll
      for (int t = 0; t < 4; ++t) {
        // fragment-linear B: one contiguous 1KB wave load
        s16x8 bfv = *(const s16x8*)(pnbf + (size_t)(((ch << 2) + t) * 16 + s) * 512 + lane * 8);
        acc[t] = __builtin_amdgcn_mfma_f32_16x16x32_bf16(af, bfv, acc[t], 0, 0, 0);
      }
    }

    // ||x||^2: lanes {l, l^16, l^32, l^48} share the same A-row
    xsq += __shfl_xor(xsq, 16);
    xsq += __shfl_xor(xsq, 32);
    if (ch == 0 && lane < 16) xsqs[wr + lane] = xsq;

    // dump C-frags: col = lane&15, row = (lane>>4)*4 + j
    const int drow = wr + ((lane >> 4) << 2);
    #pragma unroll
    for (int t = 0; t < 4; ++t) {
      const int col = (ch << 6) + (t << 4) + (lane & 15);
      #pragma unroll
      for (int j = 0; j < 4; ++j) lred[col][drow + j] = acc[t][j];
    }
  }
  __syncthreads();

  // ---- softmax (lane = row, 32 rows): w0 -> g0,g4; w1 -> g1; w2 -> g2;
  // w3 -> g3 (3-pass in LDS) ----
  if (lane < 32) {
    const float scale = 1.f / ((sqrtf(xsqs[lane]) + 1e-6f) * TAU);
    const int gfirst = (w == 0) ? 0 : w;
    const int glast  = (w == 0) ? 4 : w;     // w0 does 0 then 4 (see step)
    for (int g = gfirst; g <= glast; g += (w == 0) ? 4 : 1) {
      float mx = -1e30f;
      for (int kk = 0; kk < GK[g]; ++kk)
        mx = fmaxf(mx, lred[GB[g] + kk][lane]);
      float E = 0.f;
      for (int kk = 0; kk < GK[g]; ++kk) {
        float e = __expf((lred[GB[g] + kk][lane] - mx) * scale);
        lred[GB[g] + kk][lane] = e;
        E += e;
      }
      const float inv = 1.f / E;
      for (int kk = 0; kk < GK[g]; ++kk) lred[GB[g] + kk][lane] *= inv;
    }
  }
  __syncthreads();

  // ---- A-frags for phase 2 (c as MFMA B-operand; lred still live) ----
  s16x8 af2[4];
  {
    const int ar = wr + (lane & 15);
    #pragma unroll
    for (int s = 0; s < 4; ++s) {
      const int kbase = s * 32 + ko;
      s16x8 f;
      #pragma unroll
      for (int j = 0; j < 8; ++j) f[j] = f2bf(lred[kbase + j][ar]);
      af2[s] = f;
    }
  }
  __syncthreads();   // lred dead; smem becomes per-wave store-bounce tiles

  // ---- phase 2: out[32 x 2560] = C @ Btilde, strip-wise full-line stores --
  {
    float* ob    = smem + w * (16 * 68);                  // per-wave 16x68 tile
    float* obase = out + (size_t)(r0 + wr) * (5 * D);     // slab's global base

    phase2_group<0>(af2, mptbf, ob, obase, ch, lane);
    phase2_group<1>(af2, mptbf, ob, obase, ch, lane);
    phase2_group<2>(af2, mptbf, ob, obase, ch, lane);
    phase2_group<3>(af2, mptbf, ob, obase, ch, lane);
    phase2_group<4>(af2, mptbf, ob, obase, ch, lane);
  }
}

extern "C" void kernel_launch(void* const* d_in, const int* in_sizes, int n_in,
                              void* d_out, int out_size, void* d_ws, size_t ws_size,
                              hipStream_t stream) {
  const float* x  = (const float*)d_in[0];
  const float* P0 = (const float*)d_in[1];  // gender [2,512]
  const float* P1 = (const float*)d_in[2];  // hair   [15,512]
  const float* P2 = (const float*)d_in[3];  // top    [40,512]
  const float* P3 = (const float*)d_in[4];  // pants  [40,512]
  const float* P4 = (const float*)d_in[5];  // shoes  [24,512]
  float* out = (float*)d_out;

  unsigned short* pnbf  = (unsigned short*)d_ws;       // 128*512  u16 = 128 KiB
  unsigned short* mptbf = pnbf + 128 * 512;            // 640*512  u16 = 640 KiB

  prep_all<<<dim3(648), dim3(256), 0, stream>>>(P0, P1, P2, P3, P4, pnbf, mptbf);
  fused_main<<<dim3(1024), dim3(256), 0, stream>>>(x, pnbf, mptbf, out);
}